// Round 10
// baseline (417.081 us; speedup 1.0000x reference)
//
#include <hip/hip_runtime.h>
#include <hip/hip_bf16.h>

#define IN_DIM 512
#define OUT_DIM 512

typedef unsigned short u16;
typedef __attribute__((ext_vector_type(4))) float f32x4;
typedef __attribute__((ext_vector_type(8))) __bf16 bf16x8;

// Direct global->LDS DMA, 16B per lane. LDS dest is wave-uniform base + lane*16.
#define GLD16(gp, lp) __builtin_amdgcn_global_load_lds(                       \
    (const __attribute__((address_space(1))) void*)(gp),                      \
    (__attribute__((address_space(3))) void*)(lp), 16, 0, 0)

#define VMCNT0() asm volatile("s_waitcnt vmcnt(0)" ::: "memory")

__device__ __forceinline__ float softplus_f(float r) {
    return (r > 15.0f) ? r : log1pf(expf(r));
}

// ---------------------------------------------------------------------------
// Kernel 1: fold w = w_mu + softplus(w_rho)*w_eps -> bf16 [OUT][IN] (K-major),
//           b = b_mu + softplus(b_rho)*b_eps -> f32 [OUT], into workspace.
// ---------------------------------------------------------------------------
__global__ void prep_kernel(const float* __restrict__ wmu, const float* __restrict__ wrho,
                            const float* __restrict__ weps, const float* __restrict__ bmu,
                            const float* __restrict__ brho, const float* __restrict__ beps,
                            u16* __restrict__ wbf, float* __restrict__ bias) {
    int gid = blockIdx.x * 256 + threadIdx.x;
    int i4 = gid * 4;
    const float4 mu  = *(const float4*)(wmu + i4);
    const float4 rho = *(const float4*)(wrho + i4);
    const float4 ep  = *(const float4*)(weps + i4);
    union { __bf16 h[4]; uint2 u; } pk;
    pk.h[0] = (__bf16)(mu.x + softplus_f(rho.x) * ep.x);
    pk.h[1] = (__bf16)(mu.y + softplus_f(rho.y) * ep.y);
    pk.h[2] = (__bf16)(mu.z + softplus_f(rho.z) * ep.z);
    pk.h[3] = (__bf16)(mu.w + softplus_f(rho.w) * ep.w);
    *(uint2*)(wbf + i4) = pk.u;
    if (gid < OUT_DIM) {
        bias[gid] = bmu[gid] + softplus_f(brho[gid]) * beps[gid];
    }
}

// ---------------------------------------------------------------------------
// Kernel 1b: x (f32) -> x_bf16, streaming.
// ---------------------------------------------------------------------------
__global__ void cvt_kernel(const float* __restrict__ x, u16* __restrict__ xb) {
    const size_t base = (size_t)blockIdx.x * 8192 + threadIdx.x * 4;
#pragma unroll
    for (int i = 0; i < 8; ++i) {
        const float4 a = *(const float4*)(x + base + (size_t)i * 1024);
        union { __bf16 h[4]; uint2 u; } pk;
        pk.h[0] = (__bf16)a.x; pk.h[1] = (__bf16)a.y;
        pk.h[2] = (__bf16)a.z; pk.h[3] = (__bf16)a.w;
        *(uint2*)(xb + base + (size_t)i * 1024) = pk.u;
    }
}

// ---------------------------------------------------------------------------
// Kernel 2: y = x @ w^T + b, fused dropout.  W-STATIONARY.
//
// Grid 1024 blocks x 512 thr (8 waves). Block: 64-col W panel in LDS (64 KB,
// staged ONCE via gload_lds + single barrier), then 2 slabs x 256 rows
// (wave = 32 rows x 64 cols). K-loop: NO barriers, NO LDS staging --
// x fragments read direct from global (bf16 workspace), wf from swizzled LDS.
// Latency hidden by TLP: 16 fully-decoupled waves/CU (2 blocks, 4/SIMD).
//
// W LDS layout: [col][512K] u16, 64 chunks of 16B per col; stored chunk
//   p = g ^ (col&7)   (rule 21: linear DMA dest, source pre-permuted)
// read: p = (s*4+lk) ^ (l15&7) -> 2-way max = free.
// XCD locality: consecutive lids (8 col-bands of one row-group) land on the
// same XCD -> the 512 KB x-slab is fetched once per XCD L2, re-read 8x.
// ---------------------------------------------------------------------------
__global__ __launch_bounds__(512, 4) void bayes_gemm_ws(
    const u16* __restrict__ xb, const float* __restrict__ du,
    const u16* __restrict__ wbf, const float* __restrict__ bias,
    float* __restrict__ out)
{
    __shared__ u16 lW[64 * 512];   // 64 KB

    const int raw   = blockIdx.x;
    const int lid   = (raw & 7) * 128 + (raw >> 3);   // 1024 % 8 == 0 -> bijective
    const int nband = lid & 7;       // 0..7  : 64-col band
    const int mgrp  = lid >> 3;      // 0..127: 512-row group (2 slabs of 256)

    const int tid  = threadIdx.x;
    const int lane = tid & 63;
    const int wv   = tid >> 6;       // 0..7
    const int l15  = lane & 15;
    const int lk   = lane >> 4;      // 0..3

    const int colb = nband * 64;

    // ---- stage W panel once: wave wv covers cols wv*8..wv*8+7, 1 col per instr.
    // source chunk g = lane ^ (col&7) = lane ^ i  (wv*8 = 0 mod 8)
#pragma unroll
    for (int i = 0; i < 8; ++i) {
        const int col = wv * 8 + i;
        GLD16(wbf + (size_t)(colb + col) * IN_DIM + (lane ^ i) * 8,
              &lW[col * IN_DIM]);
    }
    VMCNT0();
    __syncthreads();   // W visible to all waves; the ONLY barrier.

#pragma unroll 1
    for (int it = 0; it < 2; ++it) {
        const int row0 = (mgrp * 2 + it) * 256 + wv * 32;   // wave's 32 rows

        f32x4 acc[2][4] = {};   // [m][n]

        const u16* px0 = xb + (size_t)(row0 +      l15) * IN_DIM + lk * 8;
        const u16* px1 = xb + (size_t)(row0 + 16 + l15) * IN_DIM + lk * 8;

#pragma unroll
        for (int s = 0; s < 16; ++s) {
            // x fragments direct from global (L2/L3; XCD-grouped reuse)
            bf16x8 af0 = *(const bf16x8*)(px0 + s * 32);
            bf16x8 af1 = *(const bf16x8*)(px1 + s * 32);

            // wf from LDS, swizzled chunk: p = (s*4+lk) ^ (l15&7)
            bf16x8 wf[4];
#pragma unroll
            for (int n = 0; n < 4; ++n) {
                int c = n * 16 + l15;
                int p = (s * 4 + lk) ^ (l15 & 7);
                wf[n] = *(const bf16x8*)&lW[c * IN_DIM + p * 8];
            }
#pragma unroll
            for (int n = 0; n < 4; ++n) {
                acc[0][n] = __builtin_amdgcn_mfma_f32_16x16x32_bf16(wf[n], af0, acc[0][n], 0, 0, 0);
                acc[1][n] = __builtin_amdgcn_mfma_f32_16x16x32_bf16(wf[n], af1, acc[1][n], 0, 0, 0);
            }
        }

        // ---- epilogue: bias + inverted dropout, dwordx4; no barrier needed
#pragma unroll
        for (int m = 0; m < 2; ++m) {
#pragma unroll
            for (int n = 0; n < 4; ++n) {
                const int colB = colb + n * 16 + lk * 4;
                const float4 b4 = *(const float4*)(bias + colB);
                size_t off = (size_t)(row0 + m * 16 + l15) * OUT_DIM + colB;
                const float4 u4 = *(const float4*)(du + off);
                float4 o;
                o.x = (acc[m][n][0] + b4.x) * ((u4.x >= 0.2f) ? 1.25f : 0.0f);
                o.y = (acc[m][n][1] + b4.y) * ((u4.y >= 0.2f) ? 1.25f : 0.0f);
                o.z = (acc[m][n][2] + b4.z) * ((u4.z >= 0.2f) ? 1.25f : 0.0f);
                o.w = (acc[m][n][3] + b4.w) * ((u4.w >= 0.2f) ? 1.25f : 0.0f);
                *(float4*)(out + off) = o;
            }
        }
    }
}

// ---------------------------------------------------------------------------
// Fallback (ws too small for x_bf16): R5-style f32-A staged kernel.
// ---------------------------------------------------------------------------
__global__ __launch_bounds__(256, 3) void bayes_gemm_f32a(
    const float* __restrict__ x, const float* __restrict__ du,
    const u16* __restrict__ wbf, const float* __restrict__ bias,
    float* __restrict__ out)
{
    __shared__ float lAf[2][128 * 32];
    __shared__ u16   lBf[2][128 * 32];

    const int raw   = blockIdx.x;
    const int lid   = (raw & 7) * 256 + (raw >> 3);
    const int mband = lid >> 2;
    const int nband = lid & 3;

    const int tid  = threadIdx.x;
    const int lane = tid & 63;
    const int wv   = tid >> 6;
    const int wm   = wv >> 1;
    const int wn   = wv & 1;
    const int l15  = lane & 15;
    const int lk   = lane >> 4;

    const int row0 = mband * 128;
    const int colb = nband * 128;

    const int arow  = wv * 8 + (lane >> 3);
    const int acswz = ((lane & 7) ^ (lane >> 3)) * 4;
    const float* gA = x + (size_t)(row0 + arow) * IN_DIM + acswz;
    const int brow  = wv * 16 + (lane >> 2);
    const int bcswz = ((lane & 3) ^ ((lane >> 3) & 3)) * 8;
    const u16* gB = wbf + (size_t)(colb + brow) * IN_DIM + bcswz;

    f32x4 acc[4][4] = {};

    auto stage = [&](int t, int buf) {
#pragma unroll
        for (int i = 0; i < 4; ++i)
            GLD16(gA + (size_t)i * 32 * IN_DIM + t * 32, &lAf[buf][i * 1024 + wv * 256]);
#pragma unroll
        for (int i = 0; i < 2; ++i)
            GLD16(gB + (size_t)i * 64 * IN_DIM + t * 32, &lBf[buf][i * 2048 + wv * 512]);
    };

    stage(0, 0);
    __syncthreads();

#pragma unroll
    for (int t = 0; t < 16; ++t) {
        const int buf = t & 1;
        if (t + 1 < 16) stage(t + 1, buf ^ 1);

        bf16x8 wf[4];
#pragma unroll
        for (int n = 0; n < 4; ++n) {
            int r = wn * 64 + n * 16 + l15;
            int p = lk ^ ((l15 >> 1) & 3);
            wf[n] = *(const bf16x8*)&lBf[buf][r * 32 + p * 8];
        }
#pragma unroll
        for (int m = 0; m < 4; ++m) {
            int r  = wm * 64 + m * 16 + l15;
            int p0 = (2 * lk)     ^ (l15 & 7);
            int p1 = (2 * lk + 1) ^ (l15 & 7);
            float4 a0 = *(const float4*)&lAf[buf][r * 32 + p0 * 4];
            float4 a1 = *(const float4*)&lAf[buf][r * 32 + p1 * 4];
            bf16x8 xf;
            xf[0] = (__bf16)a0.x; xf[1] = (__bf16)a0.y;
            xf[2] = (__bf16)a0.z; xf[3] = (__bf16)a0.w;
            xf[4] = (__bf16)a1.x; xf[5] = (__bf16)a1.y;
            xf[6] = (__bf16)a1.z; xf[7] = (__bf16)a1.w;
#pragma unroll
            for (int n = 0; n < 4; ++n)
                acc[m][n] = __builtin_amdgcn_mfma_f32_16x16x32_bf16(
                    wf[n], xf, acc[m][n], 0, 0, 0);
        }
        __syncthreads();
    }

#pragma unroll
    for (int m = 0; m < 4; ++m) {
#pragma unroll
        for (int n = 0; n < 4; ++n) {
            const int colB = colb + wn * 64 + n * 16 + lk * 4;
            const float4 b4 = *(const float4*)(bias + colB);
            size_t off = (size_t)(row0 + wm * 64 + m * 16 + l15) * OUT_DIM + colB;
            const float4 u4 = *(const float4*)(du + off);
            float4 o;
            o.x = (acc[m][n][0] + b4.x) * ((u4.x >= 0.2f) ? 1.25f : 0.0f);
            o.y = (acc[m][n][1] + b4.y) * ((u4.y >= 0.2f) ? 1.25f : 0.0f);
            o.z = (acc[m][n][2] + b4.z) * ((u4.z >= 0.2f) ? 1.25f : 0.0f);
            o.w = (acc[m][n][3] + b4.w) * ((u4.w >= 0.2f) ? 1.25f : 0.0f);
            *(float4*)(out + off) = o;
        }
    }
}

extern "C" void kernel_launch(void* const* d_in, const int* in_sizes, int n_in,
                              void* d_out, int out_size, void* d_ws, size_t ws_size,
                              hipStream_t stream) {
    const float* x    = (const float*)d_in[0];
    const float* wmu  = (const float*)d_in[1];
    const float* wrho = (const float*)d_in[2];
    const float* bmu  = (const float*)d_in[3];
    const float* brho = (const float*)d_in[4];
    const float* beps = (const float*)d_in[6];
    const float* weps = (const float*)d_in[5];
    const float* du   = (const float*)d_in[7];
    float* out = (float*)d_out;

    u16*   wbf  = (u16*)d_ws;
    float* bias = (float*)((char*)d_ws + OUT_DIM * IN_DIM * sizeof(u16));
    u16*   xb   = (u16*)((char*)d_ws + (1 << 20));   // x_bf16 at +1 MB

    const size_t need = (1u << 20) + (size_t)65536 * IN_DIM * sizeof(u16);

    prep_kernel<<<256, 256, 0, stream>>>(wmu, wrho, weps, bmu, brho, beps, wbf, bias);

    if (ws_size >= need) {
        cvt_kernel<<<4096, 256, 0, stream>>>(x, xb);
        // 128 row-groups x 8 col-bands
        bayes_gemm_ws<<<1024, 512, 0, stream>>>(xb, du, wbf, bias, out);
    } else {
        bayes_gemm_f32a<<<2048, 256, 0, stream>>>(x, du, wbf, bias, out);
    }
}

// Round 13
// 141.534 us; speedup vs baseline: 2.9468x; 2.9468x over previous
//
#include <hip/hip_runtime.h>
#include <hip/hip_bf16.h>

#define IN_DIM 512
#define OUT_DIM 512

typedef unsigned short u16;
typedef __attribute__((ext_vector_type(4))) float f32x4;
typedef __attribute__((ext_vector_type(8))) __bf16 bf16x8;

// Direct global->LDS DMA, 16B per lane. LDS dest is wave-uniform base + lane*16.
#define GLD16(gp, lp) __builtin_amdgcn_global_load_lds(                       \
    (const __attribute__((address_space(1))) void*)(gp),                      \
    (__attribute__((address_space(3))) void*)(lp), 16, 0, 0)

__device__ __forceinline__ float softplus_f(float r) {
    return (r > 15.0f) ? r : log1pf(expf(r));
}

// ---------------------------------------------------------------------------
// Kernel 1: fold w = w_mu + softplus(w_rho)*w_eps -> bf16 [OUT][IN] (K-major),
//           b = b_mu + softplus(b_rho)*b_eps -> f32 [OUT], into workspace.
// ---------------------------------------------------------------------------
__global__ void prep_kernel(const float* __restrict__ wmu, const float* __restrict__ wrho,
                            const float* __restrict__ weps, const float* __restrict__ bmu,
                            const float* __restrict__ brho, const float* __restrict__ beps,
                            u16* __restrict__ wbf, float* __restrict__ bias) {
    int gid = blockIdx.x * 256 + threadIdx.x;
    int i4 = gid * 4;
    const float4 mu  = *(const float4*)(wmu + i4);
    const float4 rho = *(const float4*)(wrho + i4);
    const float4 ep  = *(const float4*)(weps + i4);
    union { __bf16 h[4]; uint2 u; } pk;
    pk.h[0] = (__bf16)(mu.x + softplus_f(rho.x) * ep.x);
    pk.h[1] = (__bf16)(mu.y + softplus_f(rho.y) * ep.y);
    pk.h[2] = (__bf16)(mu.z + softplus_f(rho.z) * ep.z);
    pk.h[3] = (__bf16)(mu.w + softplus_f(rho.w) * ep.w);
    *(uint2*)(wbf + i4) = pk.u;
    if (gid < OUT_DIM) {
        bias[gid] = bmu[gid] + softplus_f(brho[gid]) * beps[gid];
    }
}

// ---------------------------------------------------------------------------
// Kernel 1b: x (f32) -> x_bf16, streaming (BW-bound, ~32 us).
// ---------------------------------------------------------------------------
__global__ void cvt_kernel(const float* __restrict__ x, u16* __restrict__ xb) {
    const size_t base = (size_t)blockIdx.x * 8192 + threadIdx.x * 4;
#pragma unroll
    for (int i = 0; i < 8; ++i) {
        const float4 a = *(const float4*)(x + base + (size_t)i * 1024);
        union { __bf16 h[4]; uint2 u; } pk;
        pk.h[0] = (__bf16)a.x; pk.h[1] = (__bf16)a.y;
        pk.h[2] = (__bf16)a.z; pk.h[3] = (__bf16)a.w;
        *(uint2*)(xb + base + (size_t)i * 1024) = pk.u;
    }
}

// ---------------------------------------------------------------------------
// Kernel 2: y = x @ w^T + b, fused dropout.  R8 structure, better geometry.
//
// Block 256M x 128N, 512 thr = 8 waves (4M x 2N), wave 64x64, BK=32, 16 steps.
// Per step: A 16 KB + B 8 KB staged via gload_lds (3 GLD16/thread) into
// double-buffered LDS (48 KB total -> 2 blocks/CU, 16 waves/CU).
// Grid 1024 = 2 generations (vs R8's 8) -> fewer prologue/epilogue stalls.
// Rule-21 swizzle identical to R8 (2-way max, verified): stored chunk p holds
// global chunk g = p ^ (row&3) ^ ((row>>2)&3); read ap = lk ^ (l15&3) ^ ((l15>>2)&3).
// ---------------------------------------------------------------------------
__global__ __launch_bounds__(512, 4) void bayes_gemm_kernel(
    const u16* __restrict__ xb, const float* __restrict__ du,
    const u16* __restrict__ wbf, const float* __restrict__ bias,
    float* __restrict__ out)
{
    __shared__ u16 lA[2][256 * 32];   // 16 KB per buffer
    __shared__ u16 lB[2][128 * 32];   //  8 KB per buffer

    const int raw   = blockIdx.x;
    const int lid   = (raw & 7) * 128 + (raw >> 3);   // 1024 % 8 == 0 -> bijective
    const int mband = lid >> 2;      // 0..255 : 256-row band
    const int nband = lid & 3;       // 0..3   : 128-col band (4 sibs adjacent/XCD)

    const int tid  = threadIdx.x;
    const int lane = tid & 63;
    const int wv   = tid >> 6;       // 0..7
    const int wm   = wv >> 1;        // 0..3
    const int wn   = wv & 1;         // 0..1
    const int l15  = lane & 15;
    const int lk   = lane >> 4;      // 0..3

    const int row0 = mband * 256;
    const int colb = nband * 128;

    // ---- staging geometry (linear LDS dest, source chunk pre-permuted)
    // thread t covers row/col t>>2 (plus +128 for A's second instr), chunk p=t&3.
    // g = p ^ (row&3) ^ ((row>>2)&3) = (t&3) ^ ((t>>2)&3) ^ ((t>>4)&3).
    const int sg  = ((tid & 3) ^ ((tid >> 2) & 3) ^ ((tid >> 4) & 3)) * 8;  // u16 col
    const int trc = tid >> 2;                       // 0..127
    const u16* gA = xb  + (size_t)(row0 + trc) * IN_DIM + sg;
    const u16* gB = wbf + (size_t)(colb + trc) * IN_DIM + sg;
    const int lso = trc * 32 + (tid & 3) * 8;       // u16 idx in LDS tile

    // fragment-read chunk permutation (same algebra; independent of m/n)
    const int ap = (lk ^ (l15 & 3) ^ ((l15 >> 2) & 3)) * 8;

    f32x4 acc[4][4] = {};   // [m][n]

    auto stage = [&](int t, int buf) {
        GLD16(gA + t * 32,                          &lA[buf][lso]);
        GLD16(gA + (size_t)128 * IN_DIM + t * 32,   &lA[buf][lso + 128 * 32]);
        GLD16(gB + t * 32,                          &lB[buf][lso]);
    };

    // ---- prologue
    stage(0, 0);
    __syncthreads();

#pragma unroll
    for (int t = 0; t < 16; ++t) {
        const int buf = t & 1;
        if (t + 1 < 16) stage(t + 1, buf ^ 1);   // hardware-async across compute

        bf16x8 bfr[4], afr[4];
#pragma unroll
        for (int n = 0; n < 4; ++n) {
            int c = wn * 64 + n * 16 + l15;
            bfr[n] = *(const bf16x8*)&lB[buf][c * 32 + ap];
        }
#pragma unroll
        for (int m = 0; m < 4; ++m) {
            int r = wm * 64 + m * 16 + l15;
            afr[m] = *(const bf16x8*)&lA[buf][r * 32 + ap];
        }
#pragma unroll
        for (int m = 0; m < 4; ++m)
#pragma unroll
            for (int n = 0; n < 4; ++n)
                acc[m][n] = __builtin_amdgcn_mfma_f32_16x16x32_bf16(
                    bfr[n], afr[m], acc[m][n], 0, 0, 0);

        __syncthreads();
    }

    // ---- epilogue: bias + inverted dropout, dwordx4 throughout
#pragma unroll
    for (int m = 0; m < 4; ++m) {
#pragma unroll
        for (int n = 0; n < 4; ++n) {
            const int colB = colb + wn * 64 + n * 16 + lk * 4;
            const float4 b4 = *(const float4*)(bias + colB);
            size_t off = (size_t)(row0 + wm * 64 + m * 16 + l15) * OUT_DIM + colB;
            const float4 u4 = *(const float4*)(du + off);
            float4 o;
            o.x = (acc[m][n][0] + b4.x) * ((u4.x >= 0.2f) ? 1.25f : 0.0f);
            o.y = (acc[m][n][1] + b4.y) * ((u4.y >= 0.2f) ? 1.25f : 0.0f);
            o.z = (acc[m][n][2] + b4.z) * ((u4.z >= 0.2f) ? 1.25f : 0.0f);
            o.w = (acc[m][n][3] + b4.w) * ((u4.w >= 0.2f) ? 1.25f : 0.0f);
            *(float4*)(out + off) = o;
        }
    }
}

// ---------------------------------------------------------------------------
// Fallback (ws too small for x_bf16): R5-style f32-A staged kernel.
// ---------------------------------------------------------------------------
__global__ __launch_bounds__(256, 3) void bayes_gemm_f32a(
    const float* __restrict__ x, const float* __restrict__ du,
    const u16* __restrict__ wbf, const float* __restrict__ bias,
    float* __restrict__ out)
{
    __shared__ float lAf[2][128 * 32];
    __shared__ u16   lBf[2][128 * 32];

    const int raw   = blockIdx.x;
    const int lid   = (raw & 7) * 256 + (raw >> 3);
    const int mband = lid >> 2;
    const int nband = lid & 3;

    const int tid  = threadIdx.x;
    const int lane = tid & 63;
    const int wv   = tid >> 6;
    const int wm   = wv >> 1;
    const int wn   = wv & 1;
    const int l15  = lane & 15;
    const int lk   = lane >> 4;

    const int row0 = mband * 128;
    const int colb = nband * 128;

    const int arow  = wv * 8 + (lane >> 3);
    const int acswz = ((lane & 7) ^ (lane >> 3)) * 4;
    const float* gA = x + (size_t)(row0 + arow) * IN_DIM + acswz;
    const int brow  = wv * 16 + (lane >> 2);
    const int bcswz = ((lane & 3) ^ ((lane >> 3) & 3)) * 8;
    const u16* gB = wbf + (size_t)(colb + brow) * IN_DIM + bcswz;

    f32x4 acc[4][4] = {};

    auto stage = [&](int t, int buf) {
#pragma unroll
        for (int i = 0; i < 4; ++i)
            GLD16(gA + (size_t)i * 32 * IN_DIM + t * 32, &lAf[buf][i * 1024 + wv * 256]);
#pragma unroll
        for (int i = 0; i < 2; ++i)
            GLD16(gB + (size_t)i * 64 * IN_DIM + t * 32, &lBf[buf][i * 2048 + wv * 512]);
    };

    stage(0, 0);
    __syncthreads();

#pragma unroll
    for (int t = 0; t < 16; ++t) {
        const int buf = t & 1;
        if (t + 1 < 16) stage(t + 1, buf ^ 1);

        bf16x8 wf[4];
#pragma unroll
        for (int n = 0; n < 4; ++n) {
            int r = wn * 64 + n * 16 + l15;
            int p = lk ^ ((l15 >> 1) & 3);
            wf[n] = *(const bf16x8*)&lBf[buf][r * 32 + p * 8];
        }
#pragma unroll
        for (int m = 0; m < 4; ++m) {
            int r  = wm * 64 + m * 16 + l15;
            int p0 = (2 * lk)     ^ (l15 & 7);
            int p1 = (2 * lk + 1) ^ (l15 & 7);
            float4 a0 = *(const float4*)&lAf[buf][r * 32 + p0 * 4];
            float4 a1 = *(const float4*)&lAf[buf][r * 32 + p1 * 4];
            bf16x8 xf;
            xf[0] = (__bf16)a0.x; xf[1] = (__bf16)a0.y;
            xf[2] = (__bf16)a0.z; xf[3] = (__bf16)a0.w;
            xf[4] = (__bf16)a1.x; xf[5] = (__bf16)a1.y;
            xf[6] = (__bf16)a1.z; xf[7] = (__bf16)a1.w;
#pragma unroll
            for (int n = 0; n < 4; ++n)
                acc[m][n] = __builtin_amdgcn_mfma_f32_16x16x32_bf16(
                    wf[n], xf, acc[m][n], 0, 0, 0);
        }
        __syncthreads();
    }

#pragma unroll
    for (int m = 0; m < 4; ++m) {
#pragma unroll
        for (int n = 0; n < 4; ++n) {
            const int colB = colb + wn * 64 + n * 16 + lk * 4;
            const float4 b4 = *(const float4*)(bias + colB);
            size_t off = (size_t)(row0 + wm * 64 + m * 16 + l15) * OUT_DIM + colB;
            const float4 u4 = *(const float4*)(du + off);
            float4 o;
            o.x = (acc[m][n][0] + b4.x) * ((u4.x >= 0.2f) ? 1.25f : 0.0f);
            o.y = (acc[m][n][1] + b4.y) * ((u4.y >= 0.2f) ? 1.25f : 0.0f);
            o.z = (acc[m][n][2] + b4.z) * ((u4.z >= 0.2f) ? 1.25f : 0.0f);
            o.w = (acc[m][n][3] + b4.w) * ((u4.w >= 0.2f) ? 1.25f : 0.0f);
            *(float4*)(out + off) = o;
        }
    }
}

extern "C" void kernel_launch(void* const* d_in, const int* in_sizes, int n_in,
                              void* d_out, int out_size, void* d_ws, size_t ws_size,
                              hipStream_t stream) {
    const float* x    = (const float*)d_in[0];
    const float* wmu  = (const float*)d_in[1];
    const float* wrho = (const float*)d_in[2];
    const float* bmu  = (const float*)d_in[3];
    const float* brho = (const float*)d_in[4];
    const float* weps = (const float*)d_in[5];
    const float* beps = (const float*)d_in[6];
    const float* du   = (const float*)d_in[7];
    float* out = (float*)d_out;

    u16*   wbf  = (u16*)d_ws;
    float* bias = (float*)((char*)d_ws + OUT_DIM * IN_DIM * sizeof(u16));
    u16*   xb   = (u16*)((char*)d_ws + (1 << 20));   // x_bf16 at +1 MB

    const size_t need = (1u << 20) + (size_t)65536 * IN_DIM * sizeof(u16);

    prep_kernel<<<256, 256, 0, stream>>>(wmu, wrho, weps, bmu, brho, beps, wbf, bias);

    if (ws_size >= need) {
        cvt_kernel<<<4096, 256, 0, stream>>>(x, xb);
        // 256 M-bands x 4 N-bands, 2 resident generations
        bayes_gemm_kernel<<<1024, 512, 0, stream>>>(xb, du, wbf, bias, out);
    } else {
        bayes_gemm_f32a<<<2048, 256, 0, stream>>>(x, du, wbf, bias, out);
    }
}